// Round 7
// baseline (119.989 us; speedup 1.0000x reference)
//
#include <hip/hip_runtime.h>
#include <math.h>

#define EPSV 1e-6f

typedef float f32x4 __attribute__((ext_vector_type(4)));

// ---------------------------------------------------------------------------
// Fused kernel: mask-scan prologue + straight-line partial stream + per-batch
// last-block finalize.  grid = (nchunk, B); block = D4 = 192 threads.
//
// - Prologue (R2-proven): every block derives len[b] from the mask row
//   (L2-resident after first touch).
// - Stream (R2's 68us loop structure): rows [c*len/nchunk, (c+1)*len/nchunk),
//   16B nontemporal loads (read-once data: don't pollute L1/L2), unroll 8.
// - Finalize: one ACQ_REL agent-scope atomic per block. The block that
//   completes its batch (prev == nchunk-1) reduces the batch's nchunk slots
//   in FIXED order -> bit-deterministic output regardless of which block it
//   is. Batches finalize while others still stream (no global drain).
// ---------------------------------------------------------------------------
__global__ __launch_bounds__(192) void fused_kernel(
        const float* __restrict__ feat,
        const float* __restrict__ mask,
        int* __restrict__ ctr,
        float4* __restrict__ psum,
        float4* __restrict__ psq,
        float* __restrict__ out,
        int nchunk, int T, int D4) {
    const int c   = blockIdx.x;
    const int b   = blockIdx.y;
    const int tid = threadIdx.x;

    // ---- mask-scan prologue: first negative index -> len ----
    const float* m = mask + (size_t)b * T;
    int local = T;
    if ((T & 3) == 0) {
        const float4* m4 = (const float4*)m;
        const int T4 = T >> 2;
        for (int i = tid; i < T4; i += blockDim.x) {
            float4 v = m4[i];
            if (v.x < 0.f) local = min(local, 4 * i);
            if (v.y < 0.f) local = min(local, 4 * i + 1);
            if (v.z < 0.f) local = min(local, 4 * i + 2);
            if (v.w < 0.f) local = min(local, 4 * i + 3);
        }
    } else {
        for (int t = tid; t < T; t += blockDim.x)
            if (m[t] < 0.f) local = min(local, t);
    }
    __shared__ int s[256];
    s[tid] = local;
    if (tid < 256 - 192) s[192 + tid] = T;   // pad to 256
    __syncthreads();
    #pragma unroll
    for (int off = 128; off > 0; off >>= 1) {
        if (tid < off) s[tid] = min(s[tid], s[tid + off]);
        __syncthreads();
    }
    const int first = s[0];
    const int len = (first < T) ? (first + 1) : T;

    // ---- straight-line partial stream (R2 structure) ----
    const int t0 = (int)(((long long)c * len) / nchunk);
    const int t1 = (int)(((long long)(c + 1) * len) / nchunk);

    const f32x4* f = (const f32x4*)feat + (size_t)b * T * D4;
    const int d4 = tid;

    f32x4 sm = (f32x4)(0.f);
    f32x4 sq = (f32x4)(0.f);

    #pragma unroll 8
    for (int t = t0; t < t1; ++t) {
        f32x4 v = __builtin_nontemporal_load(f + (size_t)t * D4 + d4);
        sm += v;
        sq = v * v + sq;
    }

    const size_t slot = ((size_t)b * nchunk + c) * D4 + d4;
    *(f32x4*)&psum[slot] = sm;
    *(f32x4*)&psq[slot]  = sq;

    // ---- per-batch completion atomic; last block finalizes ----
    __syncthreads();   // all threads' stores issued before the atomic
    __shared__ int s_last;
    if (tid == 0) {
        int prev = __hip_atomic_fetch_add(&ctr[b], 1, __ATOMIC_ACQ_REL,
                                          __HIP_MEMORY_SCOPE_AGENT);
        s_last = (prev == nchunk - 1);
    }
    __syncthreads();
    if (!s_last) return;

    // This block completed batch b: reduce slots [b*nchunk, b*nchunk+nchunk)
    // in fixed order (deterministic), finalize, write out[b].
    const float4* ps = psum + (size_t)b * nchunk * D4 + d4;
    const float4* pq = psq  + (size_t)b * nchunk * D4 + d4;

    float4 S = make_float4(0.f, 0.f, 0.f, 0.f);
    float4 Q = make_float4(0.f, 0.f, 0.f, 0.f);
    #pragma unroll 4
    for (int k = 0; k < nchunk; ++k) {
        float4 v = ps[(size_t)k * D4];
        float4 w = pq[(size_t)k * D4];
        S.x += v.x; S.y += v.y; S.z += v.z; S.w += v.w;
        Q.x += w.x; Q.y += w.y; Q.z += w.z; Q.w += w.w;
    }

    const float inv = 1.0f / (float)len;
    float4 mean, var;
    mean.x = S.x * inv; mean.y = S.y * inv; mean.z = S.z * inv; mean.w = S.w * inv;
    var.x = sqrtf(fmaf(-mean.x, mean.x, Q.x * inv) + EPSV);
    var.y = sqrtf(fmaf(-mean.y, mean.y, Q.y * inv) + EPSV);
    var.z = sqrtf(fmaf(-mean.z, mean.z, Q.z * inv) + EPSV);
    var.w = sqrtf(fmaf(-mean.w, mean.w, Q.w * inv) + EPSV);

    const int D = D4 * 4;
    float4* orow = (float4*)(out + (size_t)b * 2 * D);
    orow[d4]      = mean;   // [0, D)
    orow[D4 + d4] = var;    // [D, 2D)
}

// ---------------------------------------------------------------------------
extern "C" void kernel_launch(void* const* d_in, const int* in_sizes, int n_in,
                              void* d_out, int out_size, void* d_ws, size_t ws_size,
                              hipStream_t stream) {
    const float* feature  = (const float*)d_in[0];
    const float* att_mask = (const float*)d_in[1];
    float* out = (float*)d_out;

    // Shapes: in_sizes[0] = B*T*D, in_sizes[1] = B*T, out_size = B*2D
    const int D  = (int)((long long)in_sizes[0] / in_sizes[1]);   // 768
    const int B  = out_size / (2 * D);                             // 64
    const int T  = in_sizes[1] / B;                                // 2048
    const int D4 = D / 4;                                          // 192

    // Workspace: [0,4096) per-batch counters | psum | psq
    int nchunk = 16;
    size_t need;
    for (;;) {
        need = 4096 + (size_t)B * nchunk * D4 * sizeof(float4) * 2;
        if (need <= ws_size || nchunk <= 1) break;
        nchunk >>= 1;
    }

    int*    ctr  = (int*)d_ws;
    float4* psum = (float4*)((char*)d_ws + 4096);
    float4* psq  = psum + (size_t)B * nchunk * D4;

    (void)hipMemsetAsync(ctr, 0, 4096, stream);  // zero completion counters

    dim3 grid(nchunk, B);
    fused_kernel<<<grid, D4, 0, stream>>>(feature, att_mask, ctr, psum, psq,
                                          out, nchunk, T, D4);
}

// Round 8
// 66.928 us; speedup vs baseline: 1.7928x; 1.7928x over previous
//
#include <hip/hip_runtime.h>
#include <math.h>

#define EPSV 1e-6f

typedef float f32x4 __attribute__((ext_vector_type(4)));

// ---------------------------------------------------------------------------
// Kernel 1 (R2-proven structure): fused length-scan + partial sums.
// grid = (nchunk, B); block = D/4 threads (one float4 of D per thread).
// ONLY delta vs R2 (68us): feature loads are nontemporal (evict-first in L2)
// so the read-once 400MB stream doesn't evict the re-read mask rows/partials.
// ---------------------------------------------------------------------------
__global__ void partial_kernel(const float* __restrict__ feat,
                               const float* __restrict__ mask,
                               int* __restrict__ lens,
                               float4* __restrict__ psum,
                               float4* __restrict__ psq,
                               int nchunk, int T, int D4) {
    const int c = blockIdx.x;
    const int b = blockIdx.y;

    // --- first-negative scan over mask row b ---
    const float* m = mask + (size_t)b * T;
    int local = T;
    for (int t = threadIdx.x; t < T; t += blockDim.x) {
        if (m[t] < 0.0f) local = min(local, t);
    }
    __shared__ int s[256];
    s[threadIdx.x] = local;
    if (threadIdx.x < 256 - 192) s[192 + threadIdx.x] = T;  // pad (blockDim=192)
    __syncthreads();
    #pragma unroll
    for (int off = 128; off > 0; off >>= 1) {
        if ((int)threadIdx.x < off)
            s[threadIdx.x] = min(s[threadIdx.x], s[threadIdx.x + off]);
        __syncthreads();
    }
    const int first = s[0];
    const int len = (first < T) ? (first + 1) : T;

    if (c == 0 && threadIdx.x == 0) lens[b] = len;

    // --- proportional T-range for this chunk ---
    const int t0 = (int)(((long long)c * len) / nchunk);
    const int t1 = (int)(((long long)(c + 1) * len) / nchunk);

    const f32x4* f = (const f32x4*)feat + (size_t)b * T * D4;
    const int d4 = threadIdx.x;  // 0 .. D4-1

    f32x4 sm = (f32x4)(0.f);
    f32x4 sq = (f32x4)(0.f);

    #pragma unroll 8
    for (int t = t0; t < t1; ++t) {
        f32x4 v = __builtin_nontemporal_load(f + (size_t)t * D4 + d4);
        sm += v;
        sq = v * v + sq;
    }

    const size_t idx = ((size_t)b * nchunk + c) * D4 + d4;
    *(f32x4*)&psum[idx] = sm;
    *(f32x4*)&psq[idx]  = sq;
}

// ---------------------------------------------------------------------------
// Kernel 2: reduce nchunk partials, finalize mean / sqrt-var, write [B, 2D].
// grid = B blocks; block = D/4 threads.  (identical to R2)
// ---------------------------------------------------------------------------
__global__ void final_kernel(const float4* __restrict__ psum,
                             const float4* __restrict__ psq,
                             const int* __restrict__ lens,
                             float* __restrict__ out,
                             int nchunk, int D4) {
    const int b  = blockIdx.x;
    const int d4 = threadIdx.x;

    float4 s = make_float4(0.f, 0.f, 0.f, 0.f);
    float4 q = make_float4(0.f, 0.f, 0.f, 0.f);
    for (int c = 0; c < nchunk; ++c) {
        size_t idx = ((size_t)b * nchunk + c) * D4 + d4;
        float4 v = psum[idx];
        float4 w = psq[idx];
        s.x += v.x; s.y += v.y; s.z += v.z; s.w += v.w;
        q.x += w.x; q.y += w.y; q.z += w.z; q.w += w.w;
    }

    const float inv = 1.0f / (float)lens[b];
    float4 mean, var;
    mean.x = s.x * inv; mean.y = s.y * inv; mean.z = s.z * inv; mean.w = s.w * inv;
    var.x = sqrtf(fmaf(-mean.x, mean.x, q.x * inv) + EPSV);
    var.y = sqrtf(fmaf(-mean.y, mean.y, q.y * inv) + EPSV);
    var.z = sqrtf(fmaf(-mean.z, mean.z, q.z * inv) + EPSV);
    var.w = sqrtf(fmaf(-mean.w, mean.w, q.w * inv) + EPSV);

    const int D = D4 * 4;
    float4* orow = (float4*)(out + (size_t)b * 2 * D);
    orow[d4]      = mean;   // [0, D)
    orow[D4 + d4] = var;    // [D, 2D)
}

// ---------------------------------------------------------------------------
extern "C" void kernel_launch(void* const* d_in, const int* in_sizes, int n_in,
                              void* d_out, int out_size, void* d_ws, size_t ws_size,
                              hipStream_t stream) {
    const float* feature  = (const float*)d_in[0];
    const float* att_mask = (const float*)d_in[1];
    float* out = (float*)d_out;

    // Derive shapes: in_sizes[0] = B*T*D, in_sizes[1] = B*T, out_size = B*2D
    const int D  = (int)((long long)in_sizes[0] / in_sizes[1]);   // 768
    const int B  = out_size / (2 * D);                             // 64
    const int T  = in_sizes[1] / B;                                // 2048
    const int D4 = D / 4;                                          // 192

    // Workspace: [0,4096) lengths; then psum / psq float4 arrays.
    int* lens = (int*)d_ws;
    const size_t per_chunk_bytes = (size_t)B * D4 * sizeof(float4) * 2;
    int nchunk = 16;
    if (ws_size >= 4096 + per_chunk_bytes) {
        int fit = (int)((ws_size - 4096) / per_chunk_bytes);
        if (fit < nchunk) nchunk = fit;
    } else {
        nchunk = 1;
    }
    if (nchunk < 1) nchunk = 1;

    float4* psum = (float4*)((char*)d_ws + 4096);
    float4* psq  = psum + (size_t)B * nchunk * D4;

    dim3 grid(nchunk, B);
    partial_kernel<<<grid, D4, 0, stream>>>(feature, att_mask, lens, psum, psq,
                                            nchunk, T, D4);
    final_kernel<<<B, D4, 0, stream>>>(psum, psq, lens, out, nchunk, D4);
}